// Round 4
// baseline (1285.149 us; speedup 1.0000x reference)
//
#include <hip/hip_runtime.h>
#include <hip/hip_bf16.h>

typedef __attribute__((ext_vector_type(8))) short bf16x8;
typedef __attribute__((ext_vector_type(4))) float f32x4;

#define NB   256
#define TT   512
#define DDEC 512
#define DENC 1024
#define DATT 128
#define NF   32
#define KW   31
#define PW   15
#define TR   16      // tile rows
#define NTILE 32     // 32 * 16 = 512 = TT

// global -> LDS direct DMA, 16B per lane; dest = wave-uniform base + lane*16.
#define GLDS16(g, l)                                                        \
  __builtin_amdgcn_global_load_lds(                                         \
      (const __attribute__((address_space(1))) void*)(uintptr_t)(g),        \
      (__attribute__((address_space(3))) void*)(uintptr_t)(l), 16, 0, 0)

struct SMem {
  float buf[2][TR][1024];          // 131072  double-buffered enc tile (f32)
  float E[TR][137];                // 8768    energy partials (padded stride)
  __hip_bfloat16 wlocT[DATT][36];  // 9216    Wloc^T [a][f] bf16 (padded)
  float attw[TT];                  // 2048
  float qrow[DDEC];                // 2048
  float cw[NF][KW + 1];            // 4096
  float cb[NF];                    // 128
  float qv[DATT];                  // 512
  float wsc[DATT];                 // 512
  float locf[TR][34];              // 2176   per-tile conv features
  float e_red[TR];                 // 64
  float e_save[TT];                // 2048
};                                 // total ~162.7 KB

__device__ __forceinline__ float fast_tanh(float x) {
  float e = __expf(2.f * x);
  return 1.f - 2.f / (e + 1.f);
}

__device__ __forceinline__ void memfence_sched() {
  __builtin_amdgcn_sched_barrier(0);
  asm volatile("" ::: "memory");
}
__device__ __forceinline__ void bar_raw() {
  memfence_sched();
  __builtin_amdgcn_s_barrier();
  memfence_sched();
}
__device__ __forceinline__ void bar_lgkm() {
  asm volatile("s_waitcnt lgkmcnt(0)" ::: "memory");
  bar_raw();
}

// one-off: WkT[a][k] = bf16(Wk[k][a])
__global__ __launch_bounds__(256) void prep_wkt(const float* __restrict__ Wk,
                                                __hip_bfloat16* __restrict__ WkT) {
  int idx = blockIdx.x * 256 + threadIdx.x;
  int k2 = idx >> 7, a = idx & 127;
  int k = k2 * 2;
  union { ushort2 u; __hip_bfloat16 h[2]; } cv;
  cv.h[0] = __float2bfloat16(Wk[(size_t)k * DATT + a]);
  cv.h[1] = __float2bfloat16(Wk[(size_t)(k + 1) * DATT + a]);
  *reinterpret_cast<ushort2*>(WkT + (size_t)a * 1024 + k) = cv.u;
}

__global__ __launch_bounds__(1024) void flash_kernel(
    const float* __restrict__ query,
    const float* __restrict__ enc,
    const float* __restrict__ attwg,
    const float* __restrict__ Wq,
    const __hip_bfloat16* __restrict__ WkT,
    const float* __restrict__ Wloc,
    const float* __restrict__ convw,
    const float* __restrict__ convb,
    const float* __restrict__ wscore,
    float* __restrict__ out_w,
    float* __restrict__ ctx_enc) {
  __shared__ SMem sm;
  const int b = blockIdx.x, tid = threadIdx.x;
  const int lane = tid & 63, wv = tid >> 6;        // 16 waves
  const int lrow = lane & 15, lgrp = lane >> 4;
  const int ks = wv >> 1, ch = wv & 1;             // K-slice (128), col-half (64)

  // ---------------- phase 0: small loads ----------------
  if (tid < TT) {
    sm.attw[tid] = attwg[(size_t)b * TT + tid];
    sm.qrow[tid] = query[(size_t)b * DDEC + tid];
  }
  if (tid < NF * KW) sm.cw[tid / KW][tid % KW] = convw[tid];
  if (tid < NF)   sm.cb[tid]  = convb[tid];
  if (tid < DATT) sm.wsc[tid] = wscore[tid];
  for (int i = tid; i < NF * DATT; i += 1024) {
    int f = i >> 7, a = i & 127;
    sm.wlocT[a][f] = __float2bfloat16(Wloc[i]);
  }

  // ---------------- B-cache: Wk slice in 64 VGPRs, loaded once ----------------
  bf16x8 bfr[4][4];
#pragma unroll
  for (int s = 0; s < 4; ++s)
#pragma unroll
    for (int n = 0; n < 4; ++n)
      bfr[s][n] = *reinterpret_cast<const bf16x8*>(
          WkT + (size_t)(ch * 64 + n * 16 + lrow) * 1024 + ks * 128 + s * 32 + lgrp * 8);

  // stage lambda: wave wv stages row wv of tile t into buf[p], source pre-swizzled
  auto STAGE = [&](int p, int t) {
    const float* gsrc = enc + ((size_t)b * TT + t * TR + wv) * DENC;
    char* dst = (char*)&sm.buf[p][wv][0];
    const int swz = ((lane & 7) ^ (wv & 7)) | (lane & 56);
#pragma unroll
    for (int i = 0; i < 4; ++i)
      GLDS16(gsrc + (size_t)(i * 64 + swz) * 4, dst + i * 1024);
  };

  STAGE(0, 0);          // prefetch tile 0 (overlaps prologue)
  bar_lgkm();           // attw/qrow/wlocT visible

  // q projection partials (reuse E region)
  {
    float* qp = &sm.E[0][0];
    const int p = tid >> 7, a = tid & 127;
    float acc = 0.f;
    const float* wq = Wq + (size_t)(p * 64) * DATT + a;
#pragma unroll 8
    for (int dd = 0; dd < 64; ++dd)
      acc = fmaf(sm.qrow[p * 64 + dd], wq[(size_t)dd * DATT], acc);
    qp[p * 128 + a] = acc;
  }
  bar_lgkm();
  if (tid < DATT) {
    float* qp = &sm.E[0][0];
    float s = 0.f;
#pragma unroll
    for (int p = 0; p < 8; ++p) s += qp[p * 128 + tid];
    sm.qv[tid] = s;
  }
  bar_lgkm();
  // zero E (cols 0..127 of 16 rows)
  {
    int i0 = tid * 2;
    sm.E[i0 >> 7][i0 & 127] = 0.f;
    sm.E[(i0 + 1) >> 7][(i0 + 1) & 127] = 0.f;
  }
  bar_lgkm();

  // ---------------- online-softmax tile loop ----------------
  float m_run = -INFINITY, l_run = 0.f, ctxv = 0.f;
  const int d = tid;

#pragma unroll 1
  for (int t = 0; t < NTILE; ++t) {
    const int cur = t & 1;
    if (t + 1 < NTILE) {
      STAGE(cur ^ 1, t + 1);
      __builtin_amdgcn_sched_barrier(0);
      asm volatile("s_waitcnt vmcnt(4)" ::: "memory");   // retire stage(cur)
    } else {
      asm volatile("s_waitcnt vmcnt(0)" ::: "memory");
    }
    bar_raw();   // tile cur visible to all waves

    const char* rb = (const char*)&sm.buf[cur][0][0];

    // ---- MFMA: wave computes K-slice partial energies for all 16 rows ----
    f32x4 acc[4];
#pragma unroll
    for (int n = 0; n < 4; ++n) acc[n] = (f32x4){0.f, 0.f, 0.f, 0.f};
#pragma unroll
    for (int s = 0; s < 4; ++s) {
      const int c0 = ks * 32 + s * 8 + lgrp * 2;
      const int sl0 = c0 ^ (lrow & 7);
      const int sl1 = (c0 + 1) ^ (lrow & 7);
      float4 f0 = *reinterpret_cast<const float4*>(rb + lrow * 4096 + sl0 * 16);
      float4 f1 = *reinterpret_cast<const float4*>(rb + lrow * 4096 + sl1 * 16);
      union { bf16x8 v; __hip_bfloat16 h[8]; } cv;
      cv.h[0] = __float2bfloat16(f0.x); cv.h[1] = __float2bfloat16(f0.y);
      cv.h[2] = __float2bfloat16(f0.z); cv.h[3] = __float2bfloat16(f0.w);
      cv.h[4] = __float2bfloat16(f1.x); cv.h[5] = __float2bfloat16(f1.y);
      cv.h[6] = __float2bfloat16(f1.z); cv.h[7] = __float2bfloat16(f1.w);
#pragma unroll
      for (int n = 0; n < 4; ++n)
        acc[n] = __builtin_amdgcn_mfma_f32_16x16x32_bf16(cv.v, bfr[s][n], acc[n], 0, 0, 0);
    }
    // reduce partials: D[row=lgrp*4+r][col=ch*64+n*16+lrow]
#pragma unroll
    for (int n = 0; n < 4; ++n)
#pragma unroll
      for (int r = 0; r < 4; ++r)
        atomicAdd(&sm.E[lgrp * 4 + r][ch * 64 + n * 16 + lrow], acc[n][r]);
    bar_lgkm();   // E complete

    // ---- ep1: wave wv owns row wv: conv loc + tanh·wscore reduce ----
    {
      const int grow = t * TR + wv;
      if (lane < NF) {
        float a = sm.cb[lane];
#pragma unroll
        for (int k = 0; k < KW; ++k) {
          int ts = grow - PW + k;
          float x = (ts >= 0 && ts < TT) ? sm.attw[ts] : 0.f;
          a = fmaf(sm.cw[lane][k], x, a);
        }
        sm.locf[wv][lane] = a;
      }
      asm volatile("s_waitcnt lgkmcnt(0)" ::: "memory");
      __builtin_amdgcn_sched_barrier(0);
      float ep = 0.f;
#pragma unroll
      for (int h = 0; h < 2; ++h) {
        const int a = lane + h * 64;
        float lf = 0.f;
        const __hip_bfloat16* wl = &sm.wlocT[a][0];
#pragma unroll
        for (int f = 0; f < NF; ++f)
          lf = fmaf(sm.locf[wv][f], __bfloat162float(wl[f]), lf);
        float v = sm.E[wv][a] + sm.qv[a] + lf;
        ep = fmaf(fast_tanh(v), sm.wsc[a], ep);
      }
#pragma unroll
      for (int off = 1; off < 64; off <<= 1) ep += __shfl_xor(ep, off);
      if (lane == 0) { sm.e_red[wv] = ep; sm.e_save[grow] = ep; }
    }
    bar_lgkm();   // e_red ready; E reads done

    // ---- ep2: uniform online-softmax update + context accumulate from LDS ----
    {
      float er[16];
#pragma unroll
      for (int r = 0; r < 16; ++r) er[r] = sm.e_red[r];
      float mt = er[0];
#pragma unroll
      for (int r = 1; r < 16; ++r) mt = fmaxf(mt, er[r]);
      float m_new = fmaxf(m_run, mt);
      float fac = __expf(m_run - m_new);
      ctxv *= fac;
      float psum = 0.f;
#pragma unroll
      for (int r = 0; r < 16; ++r) {
        float pr = __expf(er[r] - m_new);
        psum += pr;
        float ev = *reinterpret_cast<const float*>(
            rb + r * 4096 + ((((d >> 2) ^ (r & 7)) << 4) | ((d & 3) << 2)));
        ctxv = fmaf(pr, ev, ctxv);
      }
      l_run = l_run * fac + psum;
      m_run = m_new;
      // re-zero E for next tile
      int i0 = tid * 2;
      sm.E[i0 >> 7][i0 & 127] = 0.f;
      sm.E[(i0 + 1) >> 7][(i0 + 1) & 127] = 0.f;
    }
    bar_lgkm();   // buf free for overwrite; E zeroed
  }

  // ---------------- final normalize + outputs ----------------
  float invl = 1.f / l_run;
  if (tid < TT)
    out_w[(size_t)b * TT + tid] = __expf(sm.e_save[tid] - m_run) * invl;
  ctx_enc[(size_t)b * DENC + d] = ctxv * invl;
}

// context = ctx_enc @ Wv   (256x1024 @ 1024x512)
__global__ __launch_bounds__(512) void ctx_proj_kernel(
    const float* __restrict__ ctx_enc,
    const float* __restrict__ Wv,
    float* __restrict__ out) {
  __shared__ float sc[DENC];
  const int b = blockIdx.x, tid = threadIdx.x;
  for (int i = tid; i < DENC; i += 512) sc[i] = ctx_enc[(size_t)b * DENC + i];
  __syncthreads();
  float acc = 0.f;
#pragma unroll 8
  for (int dd = 0; dd < DENC; ++dd)
    acc = fmaf(sc[dd], Wv[(size_t)dd * DDEC + tid], acc);
  out[(size_t)b * DDEC + tid] = acc;
}

extern "C" void kernel_launch(void* const* d_in, const int* in_sizes, int n_in,
                              void* d_out, int out_size, void* d_ws, size_t ws_size,
                              hipStream_t stream) {
  const float* query  = (const float*)d_in[0];
  const float* enc    = (const float*)d_in[1];
  const float* attw   = (const float*)d_in[2];
  const float* Wq     = (const float*)d_in[3];
  const float* Wk     = (const float*)d_in[4];
  const float* Wv     = (const float*)d_in[5];
  const float* Wloc   = (const float*)d_in[6];
  const float* convw  = (const float*)d_in[7];
  const float* convb  = (const float*)d_in[8];
  const float* wscore = (const float*)d_in[9];

  float* ctx     = (float*)d_out;               // [256][512]
  float* neww    = (float*)d_out + NB * TT;     // [256][512]
  float* ctx_enc = (float*)d_ws;                // [256][1024] f32 = 1MB
  __hip_bfloat16* WkT =
      (__hip_bfloat16*)((char*)d_ws + (size_t)NB * DENC * sizeof(float)); // 256KB

  hipLaunchKernelGGL(prep_wkt, dim3(256), dim3(256), 0, stream, Wk, WkT);
  hipLaunchKernelGGL(flash_kernel, dim3(NB), dim3(1024), 0, stream,
                     query, enc, attw, Wq, WkT, Wloc, convw, convb, wscore,
                     neww, ctx_enc);
  hipLaunchKernelGGL(ctx_proj_kernel, dim3(NB), dim3(512), 0, stream,
                     ctx_enc, Wv, ctx);
}

// Round 5
// 922.625 us; speedup vs baseline: 1.3929x; 1.3929x over previous
//
#include <hip/hip_runtime.h>
#include <hip/hip_bf16.h>

typedef __attribute__((ext_vector_type(8))) short bf16x8;
typedef __attribute__((ext_vector_type(4))) float f32x4;

#define NB   256
#define TT   512
#define DDEC 512
#define DENC 1024
#define DATT 128
#define NF   32
#define KW   31
#define PW   15

// global -> LDS direct DMA, 16B/lane; dest = wave-uniform base + lane*16.
#define GLDS16(g, l)                                                        \
  __builtin_amdgcn_global_load_lds(                                         \
      (const __attribute__((address_space(1))) void*)(uintptr_t)(g),        \
      (__attribute__((address_space(3))) void*)(uintptr_t)(l), 16, 0, 0)

__device__ __forceinline__ float fast_tanh(float x) {
  float e = __expf(2.f * x);
  return 1.f - 2.f / (e + 1.f);
}

// ---------- prep: WkT[a][k] = bf16(Wk[k][a]) ----------
__global__ __launch_bounds__(256) void prep_wkt(const float* __restrict__ Wk,
                                                __hip_bfloat16* __restrict__ WkT) {
  int idx = blockIdx.x * 256 + threadIdx.x;
  int k2 = idx >> 7, a = idx & 127;
  int k = k2 * 2;
  union { ushort2 u; __hip_bfloat16 h[2]; } cv;
  cv.h[0] = __float2bfloat16(Wk[(size_t)k * DATT + a]);
  cv.h[1] = __float2bfloat16(Wk[(size_t)(k + 1) * DATT + a]);
  *reinterpret_cast<ushort2*>(WkT + (size_t)a * 1024 + k) = cv.u;
}

// ---------- prep: qv[b][a] = query[b,:] @ Wq[:,a] ----------
__global__ __launch_bounds__(128) void prep_qv(const float* __restrict__ query,
                                               const float* __restrict__ Wq,
                                               float* __restrict__ qvg) {
  __shared__ float qr[DDEC];
  const int b = blockIdx.x, tid = threadIdx.x;
  for (int i = tid; i < DDEC; i += 128) qr[i] = query[(size_t)b * DDEC + i];
  __syncthreads();
  float a0 = 0.f, a1 = 0.f, a2 = 0.f, a3 = 0.f;
#pragma unroll 4
  for (int d = 0; d < DDEC; d += 4) {
    a0 = fmaf(qr[d + 0], Wq[(size_t)(d + 0) * DATT + tid], a0);
    a1 = fmaf(qr[d + 1], Wq[(size_t)(d + 1) * DATT + tid], a1);
    a2 = fmaf(qr[d + 2], Wq[(size_t)(d + 2) * DATT + tid], a2);
    a3 = fmaf(qr[d + 3], Wq[(size_t)(d + 3) * DATT + tid], a3);
  }
  qvg[(size_t)b * DATT + tid] = (a0 + a1) + (a2 + a3);
}

// ---------- K1: energies for 128 t-rows per block ----------
struct K1SMem {
  float astage[8][2][16][32];      // 8 waves x dbuf x 16 rows x 32 f32  32768
  __hip_bfloat16 locA[8][16][32];  // conv feats per wave                 8192
  __hip_bfloat16 locBt[128][32];   // Wloc^T [a][f]                       8192
  float attw_loc[160];             // attw halo for this 128-row chunk     640
  float qv[DATT];                  //                                      512
  float wsc[DATT];                 //                                      512
};                                 // ~50.8 KB -> 3 blocks/CU

__global__ __launch_bounds__(512, 6) void energy_kernel(
    const float* __restrict__ enc,
    const float* __restrict__ attwg,
    const __hip_bfloat16* __restrict__ WkT,
    const float* __restrict__ qvg,
    const float* __restrict__ Wloc,
    const float* __restrict__ convw,
    const float* __restrict__ convb,
    const float* __restrict__ wscore,
    float* __restrict__ energy_ws) {
  __shared__ K1SMem sm;
  const int b = blockIdx.x >> 2, q = blockIdx.x & 3;
  const int tid = threadIdx.x;
  const int lane = tid & 63, wv = tid >> 6;     // 8 waves, 16 rows each
  const int lrow = lane & 15, lgrp = lane >> 4;

  // phase 0: fills
  if (tid < DATT) {
    sm.qv[tid] = qvg[(size_t)b * DATT + tid];
    sm.wsc[tid] = wscore[tid];
  }
  if (tid < 160) {
    int g = q * 128 - PW + tid;
    sm.attw_loc[tid] = (g >= 0 && g < TT) ? attwg[(size_t)b * TT + g] : 0.f;
  }
  for (int i = tid; i < NF * DATT; i += 512) {
    int f = i >> 7, a = i & 127;
    sm.locBt[a][f] = __float2bfloat16(Wloc[i]);
  }
  __syncthreads();

  // conv weights -> regs (lane owns filter f = lane&31)
  const int f = lane & 31;
  float cwreg[KW];
#pragma unroll
  for (int k = 0; k < KW; ++k) cwreg[k] = convw[f * KW + k];
  const float cbreg = convb[f];

  // prologue: prefetch tile 0 (A via DMA, B via regs)
  const float* gsrc_base =
      enc + ((size_t)b * TT + q * 128 + wv * 16 + (lane >> 3)) * DENC +
      (((lane & 7) ^ (lane >> 3)) << 2);
  const __hip_bfloat16* pb = WkT + (size_t)lrow * 1024 + lgrp * 8;

  bf16x8 barrA[8], barrB[8];
  {
    char* d0 = (char*)&sm.astage[wv][0][0][0];
    GLDS16(gsrc_base, d0);
    GLDS16(gsrc_base + (size_t)8 * DENC, d0 + 1024);
#pragma unroll
    for (int n = 0; n < 8; ++n)
      barrA[n] = *reinterpret_cast<const bf16x8*>(pb + (size_t)n * 16384);
  }

  // conv loc features for this wave's 16 rows (overlaps DMA latency)
  {
    float att[38];
    const int rbase = (lane >> 5) * 8;          // 0 or 8
#pragma unroll
    for (int i = 0; i < 38; ++i) att[i] = sm.attw_loc[wv * 16 + rbase + i];
#pragma unroll
    for (int rr = 0; rr < 8; ++rr) {
      float acc = cbreg;
#pragma unroll
      for (int k = 0; k < KW; ++k) acc = fmaf(cwreg[k], att[rr + k], acc);
      sm.locA[wv][rbase + rr][f] = __float2bfloat16(acc);
    }
  }

  // loc MFMA (K=32) initializes acc
  f32x4 acc[8];
  {
    bf16x8 af = *reinterpret_cast<const bf16x8*>(&sm.locA[wv][lrow][lgrp * 8]);
#pragma unroll
    for (int n = 0; n < 8; ++n) {
      bf16x8 bl = *reinterpret_cast<const bf16x8*>(&sm.locBt[n * 16 + lrow][lgrp * 8]);
      acc[n] = __builtin_amdgcn_mfma_f32_16x16x32_bf16(
          af, bl, (f32x4){0.f, 0.f, 0.f, 0.f}, 0, 0, 0);
    }
  }

#define K1_STEP(BUFSEL, BNOW, BNEXT, TILE)                                    \
  {                                                                           \
    if ((TILE) + 1 < 32) {                                                    \
      const int nt_ = (TILE) + 1;                                             \
      char* d0_ = (char*)&sm.astage[wv][(BUFSEL) ^ 1][0][0];                  \
      GLDS16(gsrc_base + nt_ * 32, d0_);                                      \
      GLDS16(gsrc_base + nt_ * 32 + (size_t)8 * DENC, d0_ + 1024);            \
      _Pragma("unroll")                                                       \
      for (int n = 0; n < 8; ++n)                                             \
        BNEXT[n] = *reinterpret_cast<const bf16x8*>(                          \
            pb + (size_t)n * 16384 + nt_ * 32);                               \
      __builtin_amdgcn_sched_barrier(0);                                      \
      asm volatile("s_waitcnt vmcnt(10)" ::: "memory");                       \
      __builtin_amdgcn_sched_barrier(0);                                      \
    } else {                                                                  \
      __builtin_amdgcn_sched_barrier(0);                                      \
      asm volatile("s_waitcnt vmcnt(0)" ::: "memory");                        \
      __builtin_amdgcn_sched_barrier(0);                                      \
    }                                                                         \
    const char* rb_ = (const char*)&sm.astage[wv][(BUFSEL)][0][0];            \
    const int x_ = lrow & 7;                                                  \
    float4 f0_ = *reinterpret_cast<const float4*>(                            \
        rb_ + lrow * 128 + (((2 * lgrp) ^ x_) << 4));                         \
    float4 f1_ = *reinterpret_cast<const float4*>(                            \
        rb_ + lrow * 128 + (((2 * lgrp + 1) ^ x_) << 4));                     \
    union { bf16x8 v; __hip_bfloat16 h[8]; } cv_;                             \
    cv_.h[0] = __float2bfloat16(f0_.x); cv_.h[1] = __float2bfloat16(f0_.y);   \
    cv_.h[2] = __float2bfloat16(f0_.z); cv_.h[3] = __float2bfloat16(f0_.w);   \
    cv_.h[4] = __float2bfloat16(f1_.x); cv_.h[5] = __float2bfloat16(f1_.y);   \
    cv_.h[6] = __float2bfloat16(f1_.z); cv_.h[7] = __float2bfloat16(f1_.w);   \
    _Pragma("unroll")                                                         \
    for (int n = 0; n < 8; ++n)                                               \
      acc[n] = __builtin_amdgcn_mfma_f32_16x16x32_bf16(                       \
          cv_.v, BNOW[n], acc[n], 0, 0, 0);                                   \
  }

#pragma unroll 1
  for (int c = 0; c < 32; c += 2) {
    K1_STEP(0, barrA, barrB, c)
    K1_STEP(1, barrB, barrA, c + 1)
  }
#undef K1_STEP

  // epilogue: e[row] = sum_a tanh(D + qv[a]) * wsc[a]
#pragma unroll
  for (int r = 0; r < 4; ++r) {
    float e = 0.f;
#pragma unroll
    for (int n = 0; n < 8; ++n) {
      const int col = n * 16 + lrow;
      float v = acc[n][r] + sm.qv[col];
      e = fmaf(fast_tanh(v), sm.wsc[col], e);
    }
    e += __shfl_xor(e, 1);
    e += __shfl_xor(e, 2);
    e += __shfl_xor(e, 4);
    e += __shfl_xor(e, 8);
    if (lrow == 0)
      energy_ws[(size_t)b * TT + q * 128 + wv * 16 + lgrp * 4 + r] = e;
  }
}

// ---------- K2: softmax over T ----------
__global__ __launch_bounds__(512) void softmax_kernel(
    const float* __restrict__ energy_ws, float* __restrict__ out_w) {
  __shared__ float red[8];
  __shared__ float scal[2];
  const int b = blockIdx.x, tid = threadIdx.x;
  const int lane = tid & 63, wv = tid >> 6;
  const float e0 = energy_ws[(size_t)b * TT + tid];
  float m1 = e0;
#pragma unroll
  for (int off = 1; off < 64; off <<= 1) m1 = fmaxf(m1, __shfl_xor(m1, off));
  if (lane == 0) red[wv] = m1;
  __syncthreads();
  if (tid == 0) {
    float mm = red[0];
#pragma unroll
    for (int i = 1; i < 8; ++i) mm = fmaxf(mm, red[i]);
    scal[0] = mm;
  }
  __syncthreads();
  const float ex = __expf(e0 - scal[0]);
  float s1 = ex;
#pragma unroll
  for (int off = 1; off < 64; off <<= 1) s1 += __shfl_xor(s1, off);
  if (lane == 0) red[wv] = s1;
  __syncthreads();
  if (tid == 0) {
    float ss = 0.f;
#pragma unroll
    for (int i = 0; i < 8; ++i) ss += red[i];
    scal[1] = 1.f / ss;
  }
  __syncthreads();
  out_w[(size_t)b * TT + tid] = ex * scal[1];
}

// ---------- K3: context partials over 128-row chunks ----------
__global__ __launch_bounds__(256) void ctx_partial_kernel(
    const float* __restrict__ enc, const float* __restrict__ w,
    float* __restrict__ ctxp) {
  __shared__ float ws[128];
  const int b = blockIdx.x >> 2, q = blockIdx.x & 3;
  const int tid = threadIdx.x;
  if (tid < 128) ws[tid] = w[(size_t)b * TT + q * 128 + tid];
  __syncthreads();
  const float* base = enc + ((size_t)b * TT + q * 128) * DENC + tid * 4;
  float4 a = {0.f, 0.f, 0.f, 0.f};
#pragma unroll 8
  for (int r = 0; r < 128; ++r) {
    float4 v = *reinterpret_cast<const float4*>(base + (size_t)r * DENC);
    const float wt = ws[r];
    a.x = fmaf(wt, v.x, a.x);
    a.y = fmaf(wt, v.y, a.y);
    a.z = fmaf(wt, v.z, a.z);
    a.w = fmaf(wt, v.w, a.w);
  }
  *reinterpret_cast<float4*>(ctxp + ((size_t)(b * 4 + q)) * DENC + tid * 4) = a;
}

// ---------- K4: reduce partials + context @ Wv ----------
__global__ __launch_bounds__(512) void ctx_proj_kernel(
    const float* __restrict__ ctxp, const float* __restrict__ Wv,
    float* __restrict__ out) {
  __shared__ float sc[DENC];
  const int b = blockIdx.x, tid = threadIdx.x;
  for (int i = tid; i < DENC; i += 512) {
    float s = 0.f;
#pragma unroll
    for (int qq = 0; qq < 4; ++qq) s += ctxp[((size_t)(b * 4 + qq)) * DENC + i];
    sc[i] = s;
  }
  __syncthreads();
  float acc = 0.f;
#pragma unroll 8
  for (int dd = 0; dd < DENC; ++dd)
    acc = fmaf(sc[dd], Wv[(size_t)dd * DDEC + tid], acc);
  out[(size_t)b * DDEC + tid] = acc;
}

extern "C" void kernel_launch(void* const* d_in, const int* in_sizes, int n_in,
                              void* d_out, int out_size, void* d_ws, size_t ws_size,
                              hipStream_t stream) {
  const float* query  = (const float*)d_in[0];
  const float* enc    = (const float*)d_in[1];
  const float* attw   = (const float*)d_in[2];
  const float* Wq     = (const float*)d_in[3];
  const float* Wk     = (const float*)d_in[4];
  const float* Wv     = (const float*)d_in[5];
  const float* Wloc   = (const float*)d_in[6];
  const float* convw  = (const float*)d_in[7];
  const float* convb  = (const float*)d_in[8];
  const float* wscore = (const float*)d_in[9];

  float* ctx  = (float*)d_out;               // [256][512]
  float* neww = (float*)d_out + NB * TT;     // [256][512]

  char* ws = (char*)d_ws;
  float* ctxp      = (float*)ws;                         // 256*4*1024 f32 = 4MB
  __hip_bfloat16* WkT = (__hip_bfloat16*)(ws + 4194304); // 256KB
  float* qvg       = (float*)(ws + 4194304 + 262144);    // 128KB
  float* energy_ws = (float*)(ws + 4194304 + 262144 + 131072); // 512KB

  hipLaunchKernelGGL(prep_wkt, dim3(256), dim3(256), 0, stream, Wk, WkT);
  hipLaunchKernelGGL(prep_qv, dim3(NB), dim3(128), 0, stream, query, Wq, qvg);
  hipLaunchKernelGGL(energy_kernel, dim3(NB * 4), dim3(512), 0, stream,
                     enc, attw, WkT, qvg, Wloc, convw, convb, wscore, energy_ws);
  hipLaunchKernelGGL(softmax_kernel, dim3(NB), dim3(512), 0, stream,
                     energy_ws, neww);
  hipLaunchKernelGGL(ctx_partial_kernel, dim3(NB * 4), dim3(256), 0, stream,
                     enc, neww, ctxp);
  hipLaunchKernelGGL(ctx_proj_kernel, dim3(NB), dim3(512), 0, stream,
                     ctxp, Wv, ctx);
}

// Round 6
// 352.673 us; speedup vs baseline: 3.6440x; 2.6161x over previous
//
#include <hip/hip_runtime.h>
#include <hip/hip_bf16.h>

typedef __attribute__((ext_vector_type(8))) short bf16x8;
typedef __attribute__((ext_vector_type(4))) float f32x4;

#define NB   256
#define TT   512
#define DDEC 512
#define DENC 1024
#define DATT 128
#define NF   32
#define KW   31
#define PW   15

__device__ __forceinline__ float fast_tanh(float x) {
  float e = __expf(2.f * x);
  return 1.f - 2.f / (e + 1.f);
}

// ---------- prep: WkT[a][k] = bf16(Wk[k][a]) ----------
__global__ __launch_bounds__(256) void prep_wkt(const float* __restrict__ Wk,
                                                __hip_bfloat16* __restrict__ WkT) {
  int idx = blockIdx.x * 256 + threadIdx.x;
  int k2 = idx >> 7, a = idx & 127;
  int k = k2 * 2;
  union { ushort2 u; __hip_bfloat16 h[2]; } cv;
  cv.h[0] = __float2bfloat16(Wk[(size_t)k * DATT + a]);
  cv.h[1] = __float2bfloat16(Wk[(size_t)(k + 1) * DATT + a]);
  *reinterpret_cast<ushort2*>(WkT + (size_t)a * 1024 + k) = cv.u;
}

// ---------- prep: qv[b][a] = query[b,:] @ Wq[:,a] ----------
__global__ __launch_bounds__(128) void prep_qv(const float* __restrict__ query,
                                               const float* __restrict__ Wq,
                                               float* __restrict__ qvg) {
  __shared__ float qr[DDEC];
  const int b = blockIdx.x, tid = threadIdx.x;
  for (int i = tid; i < DDEC; i += 128) qr[i] = query[(size_t)b * DDEC + i];
  __syncthreads();
  float a0 = 0.f, a1 = 0.f, a2 = 0.f, a3 = 0.f;
#pragma unroll 4
  for (int d = 0; d < DDEC; d += 4) {
    a0 = fmaf(qr[d + 0], Wq[(size_t)(d + 0) * DATT + tid], a0);
    a1 = fmaf(qr[d + 1], Wq[(size_t)(d + 1) * DATT + tid], a1);
    a2 = fmaf(qr[d + 2], Wq[(size_t)(d + 2) * DATT + tid], a2);
    a3 = fmaf(qr[d + 3], Wq[(size_t)(d + 3) * DATT + tid], a3);
  }
  qvg[(size_t)b * DATT + tid] = (a0 + a1) + (a2 + a3);
}

struct SMem {
  union {
    struct {
      __hip_bfloat16 locA[512][40];   // conv feats per row    40KB
      __hip_bfloat16 locBt[128][40];  // Wloc^T [a][f]         10KB
    } l;
    float part[8][1024];              // phase-2 partials      32KB
  } u;
  float attw[TT];      // 2KB
  float cw[NF][32];    // 4KB
  float cb[NF];
  float qv[DATT];
  float wsc[DATT];
  float energy[TT];    // 2KB
  float red[8];
  float scal[2];
};                     // ~61 KB

__global__ __launch_bounds__(512, 2) void pass1_kernel(
    const float* __restrict__ enc,
    const float* __restrict__ attwg,
    const __hip_bfloat16* __restrict__ WkT,
    const float* __restrict__ qvg,
    const float* __restrict__ Wloc,
    const float* __restrict__ convw,
    const float* __restrict__ convb,
    const float* __restrict__ wscore,
    float* __restrict__ out_w,
    float* __restrict__ ctx_enc) {
  __shared__ SMem sm;
  const int b = blockIdx.x, tid = threadIdx.x;
  const int lane = tid & 63, wv = tid >> 6;   // 8 waves, 64 rows each
  const int lrow = lane & 15, lgrp = lane >> 4;

  // ---------------- phase 0: small fills ----------------
  sm.attw[tid] = attwg[(size_t)b * TT + tid];
  if (tid < NF * KW) sm.cw[tid / KW][tid % KW] = convw[tid];
  if (tid < NF)   sm.cb[tid]  = convb[tid];
  if (tid < DATT) {
    sm.qv[tid]  = qvg[(size_t)b * DATT + tid];
    sm.wsc[tid] = wscore[tid];
  }
  for (int i = tid; i < NF * DATT; i += 512) {
    int f = i >> 7, a = i & 127;
    sm.u.l.locBt[a][f] = __float2bfloat16(Wloc[i]);
  }
  __syncthreads();

  // A/B pointers for the K-loop; issue first A-loads early (hide under conv)
  const float* pa = enc + ((size_t)b * TT + wv * 64 + lrow) * DENC + lgrp * 8;
  const __hip_bfloat16* pb = WkT + (size_t)lrow * 1024 + lgrp * 8;

  float4 aqA[8], aqB[8];
#pragma unroll
  for (int m = 0; m < 4; ++m) {
    const float* p_ = pa + (size_t)m * 16 * DENC;
    aqA[2 * m]     = *reinterpret_cast<const float4*>(p_);
    aqA[2 * m + 1] = *reinterpret_cast<const float4*>(p_ + 4);
  }

  // conv1d location features (wave-local: thread t -> row t of its own wave)
  {
    const int t = tid;
#pragma unroll
    for (int f = 0; f < NF; ++f) {
      float a = sm.cb[f];
      for (int k = 0; k < KW; ++k) {
        int ts = t - PW + k;
        float x = (ts >= 0 && ts < TT) ? sm.attw[ts] : 0.f;
        a = fmaf(sm.cw[f][k], x, a);
      }
      sm.u.l.locA[t][f] = __float2bfloat16(a);
    }
  }

  // loc MFMA (K=32) initializes acc[4][8] (wave-local locA rows; locBt after sync)
  f32x4 acc[4][8];
  {
    bf16x8 bl[8];
#pragma unroll
    for (int n = 0; n < 8; ++n)
      bl[n] = *reinterpret_cast<const bf16x8*>(&sm.u.l.locBt[n * 16 + lrow][lgrp * 8]);
#pragma unroll
    for (int m = 0; m < 4; ++m) {
      bf16x8 af = *reinterpret_cast<const bf16x8*>(
          &sm.u.l.locA[wv * 64 + m * 16 + lrow][lgrp * 8]);
#pragma unroll
      for (int n = 0; n < 8; ++n)
        acc[m][n] = __builtin_amdgcn_mfma_f32_16x16x32_bf16(
            af, bl[n], (f32x4){0.f, 0.f, 0.f, 0.f}, 0, 0, 0);
    }
  }

  // ---------------- K-loop: direct-load, depth-2 register queues ----------
  bf16x8 bb[8];

#define LOADA(Q, S)                                                           \
  {                                                                           \
    _Pragma("unroll") for (int m = 0; m < 4; ++m) {                           \
      const float* p_ = pa + (size_t)m * 16 * DENC + (S) * 32;                \
      Q[2 * m]     = *reinterpret_cast<const float4*>(p_);                    \
      Q[2 * m + 1] = *reinterpret_cast<const float4*>(p_ + 4);                \
    }                                                                         \
  }
#define LOADB(S)                                                              \
  {                                                                           \
    _Pragma("unroll") for (int n = 0; n < 8; ++n)                             \
      bb[n] = *reinterpret_cast<const bf16x8*>(                               \
          pb + (size_t)n * 16 * 1024 + (S) * 32);                             \
  }
#define MFMA_STEP(Q)                                                          \
  {                                                                           \
    _Pragma("unroll") for (int m = 0; m < 4; ++m) {                           \
      union { bf16x8 v; __hip_bfloat16 h[8]; } cv_;                           \
      cv_.h[0] = __float2bfloat16(Q[2 * m].x);                                \
      cv_.h[1] = __float2bfloat16(Q[2 * m].y);                                \
      cv_.h[2] = __float2bfloat16(Q[2 * m].z);                                \
      cv_.h[3] = __float2bfloat16(Q[2 * m].w);                                \
      cv_.h[4] = __float2bfloat16(Q[2 * m + 1].x);                            \
      cv_.h[5] = __float2bfloat16(Q[2 * m + 1].y);                            \
      cv_.h[6] = __float2bfloat16(Q[2 * m + 1].z);                            \
      cv_.h[7] = __float2bfloat16(Q[2 * m + 1].w);                            \
      _Pragma("unroll") for (int n = 0; n < 8; ++n)                           \
        acc[m][n] = __builtin_amdgcn_mfma_f32_16x16x32_bf16(                  \
            cv_.v, bb[n], acc[m][n], 0, 0, 0);                                \
    }                                                                         \
  }

#pragma unroll 1
  for (int s = 0; s < 32; s += 2) {
    LOADB(s);
    LOADA(aqB, s + 1);
    MFMA_STEP(aqA);            // uses aqA + bb(s); aqB/aqA(s+2) stay in flight
    LOADB(s + 1);
    if (s + 2 < 32) LOADA(aqA, s + 2);
    MFMA_STEP(aqB);            // bb(s+1) latency hidden under MFMA_STEP(aqA)
  }
#undef LOADA
#undef LOADB
#undef MFMA_STEP

  // ---------------- epilogue: energies ----------------
#pragma unroll
  for (int m = 0; m < 4; ++m) {
#pragma unroll
    for (int r = 0; r < 4; ++r) {
      float e = 0.f;
#pragma unroll
      for (int n = 0; n < 8; ++n) {
        const int col = n * 16 + lrow;
        float v = acc[m][n][r] + sm.qv[col];
        e = fmaf(fast_tanh(v), sm.wsc[col], e);
      }
      e += __shfl_xor(e, 1);
      e += __shfl_xor(e, 2);
      e += __shfl_xor(e, 4);
      e += __shfl_xor(e, 8);
      if (lrow == 0) sm.energy[wv * 64 + m * 16 + lgrp * 4 + r] = e;
    }
  }
  __syncthreads();

  // ---------------- softmax over T=512 ----------------
  const float e0 = sm.energy[tid];
  float m1 = e0;
#pragma unroll
  for (int off = 1; off < 64; off <<= 1) m1 = fmaxf(m1, __shfl_xor(m1, off));
  if (lane == 0) sm.red[wv] = m1;
  __syncthreads();
  if (tid == 0) {
    float mm = sm.red[0];
#pragma unroll
    for (int i = 1; i < 8; ++i) mm = fmaxf(mm, sm.red[i]);
    sm.scal[0] = mm;
  }
  __syncthreads();
  const float ex = __expf(e0 - sm.scal[0]);
  float s1 = ex;
#pragma unroll
  for (int off = 1; off < 64; off <<= 1) s1 += __shfl_xor(s1, off);
  if (lane == 0) sm.red[wv] = s1;
  __syncthreads();
  if (tid == 0) {
    float ss = 0.f;
#pragma unroll
    for (int i = 0; i < 8; ++i) ss += sm.red[i];
    sm.scal[1] = 1.f / ss;
  }
  __syncthreads();
  const float wnorm = ex * sm.scal[1];
  sm.energy[tid] = wnorm;
  out_w[(size_t)b * TT + tid] = wnorm;
  __syncthreads();

  // ---------------- phase 2: ctx_enc[b,d] = sum_t w[t]*enc[b,t,d] ----------
  float4 a0 = {0,0,0,0}, a1 = {0,0,0,0}, a2 = {0,0,0,0}, a3 = {0,0,0,0};
  const int t0 = wv * 64;
#pragma unroll 2
  for (int tt = 0; tt < 64; ++tt) {
    const int t = t0 + tt;
    const float wt = sm.energy[t];
    const float4* row =
        reinterpret_cast<const float4*>(enc + ((size_t)b * TT + t) * DENC);
    float4 v0 = row[lane];
    float4 v1 = row[64 + lane];
    float4 v2 = row[128 + lane];
    float4 v3 = row[192 + lane];
    a0.x = fmaf(wt, v0.x, a0.x); a0.y = fmaf(wt, v0.y, a0.y);
    a0.z = fmaf(wt, v0.z, a0.z); a0.w = fmaf(wt, v0.w, a0.w);
    a1.x = fmaf(wt, v1.x, a1.x); a1.y = fmaf(wt, v1.y, a1.y);
    a1.z = fmaf(wt, v1.z, a1.z); a1.w = fmaf(wt, v1.w, a1.w);
    a2.x = fmaf(wt, v2.x, a2.x); a2.y = fmaf(wt, v2.y, a2.y);
    a2.z = fmaf(wt, v2.z, a2.z); a2.w = fmaf(wt, v2.w, a2.w);
    a3.x = fmaf(wt, v3.x, a3.x); a3.y = fmaf(wt, v3.y, a3.y);
    a3.z = fmaf(wt, v3.z, a3.z); a3.w = fmaf(wt, v3.w, a3.w);
  }
  *reinterpret_cast<float4*>(&sm.u.part[wv][lane * 4])       = a0;
  *reinterpret_cast<float4*>(&sm.u.part[wv][256 + lane * 4]) = a1;
  *reinterpret_cast<float4*>(&sm.u.part[wv][512 + lane * 4]) = a2;
  *reinterpret_cast<float4*>(&sm.u.part[wv][768 + lane * 4]) = a3;
  __syncthreads();
#pragma unroll
  for (int h = 0; h < 2; ++h) {
    const int d = tid + h * 512;
    float s = 0.f;
#pragma unroll
    for (int w = 0; w < 8; ++w) s += sm.u.part[w][d];
    ctx_enc[(size_t)b * DENC + d] = s;
  }
}

// context = ctx_enc @ Wv   (256x1024 @ 1024x512)
__global__ __launch_bounds__(512) void ctx_proj_kernel(
    const float* __restrict__ ctx_enc,
    const float* __restrict__ Wv,
    float* __restrict__ out) {
  __shared__ float sc[DENC];
  const int b = blockIdx.x, tid = threadIdx.x;
  for (int i = tid; i < DENC; i += 512) sc[i] = ctx_enc[(size_t)b * DENC + i];
  __syncthreads();
  float acc = 0.f;
#pragma unroll 8
  for (int dd = 0; dd < DENC; ++dd)
    acc = fmaf(sc[dd], Wv[(size_t)dd * DDEC + tid], acc);
  out[(size_t)b * DDEC + tid] = acc;
}

extern "C" void kernel_launch(void* const* d_in, const int* in_sizes, int n_in,
                              void* d_out, int out_size, void* d_ws, size_t ws_size,
                              hipStream_t stream) {
  const float* query  = (const float*)d_in[0];
  const float* enc    = (const float*)d_in[1];
  const float* attw   = (const float*)d_in[2];
  const float* Wq     = (const float*)d_in[3];
  const float* Wk     = (const float*)d_in[4];
  const float* Wv     = (const float*)d_in[5];
  const float* Wloc   = (const float*)d_in[6];
  const float* convw  = (const float*)d_in[7];
  const float* convb  = (const float*)d_in[8];
  const float* wscore = (const float*)d_in[9];

  float* ctx  = (float*)d_out;               // [256][512]
  float* neww = (float*)d_out + NB * TT;     // [256][512]

  char* ws = (char*)d_ws;
  float* ctx_enc = (float*)ws;                              // 1MB
  __hip_bfloat16* WkT = (__hip_bfloat16*)(ws + 1048576);    // 256KB
  float* qvg = (float*)(ws + 1048576 + 262144);             // 128KB

  hipLaunchKernelGGL(prep_wkt, dim3(256), dim3(256), 0, stream, Wk, WkT);
  hipLaunchKernelGGL(prep_qv, dim3(NB), dim3(128), 0, stream, query, Wq, qvg);
  hipLaunchKernelGGL(pass1_kernel, dim3(NB), dim3(512), 0, stream,
                     enc, attw, WkT, qvg, Wloc, convw, convb, wscore,
                     neww, ctx_enc);
  hipLaunchKernelGGL(ctx_proj_kernel, dim3(NB), dim3(512), 0, stream,
                     ctx_enc, Wv, ctx);
}